// Round 6
// baseline (225.116 us; speedup 1.0000x reference)
//
#include <hip/hip_runtime.h>
#include <hip/hip_bf16.h>
#include <hip/hip_cooperative_groups.h>

namespace cg = cooperative_groups;

// Shapes: M=128, H=256, F=256, T=4, I=2, NSEM=57
#define M_ 128
#define H_ 256
#define F_ 256
#define T_ 4
#define NSEM_ 57

typedef __attribute__((ext_vector_type(8))) short bf16x8;
typedef __attribute__((ext_vector_type(4))) float f32x4;

__device__ __forceinline__ float4 ld4(const float* p) { return *reinterpret_cast<const float4*>(p); }
__device__ __forceinline__ void st4(float* p, float4 v) { *reinterpret_cast<float4*>(p) = v; }
__device__ __forceinline__ float4 add4(float4 a, float4 b) { return make_float4(a.x+b.x, a.y+b.y, a.z+b.z, a.w+b.w); }
__device__ __forceinline__ float4 relu4(float4 a) { return make_float4(fmaxf(a.x,0.f), fmaxf(a.y,0.f), fmaxf(a.z,0.f), fmaxf(a.w,0.f)); }
__device__ __forceinline__ float4 fma4(float s, float4 w, float4 c) { return make_float4(fmaf(s,w.x,c.x), fmaf(s,w.y,c.y), fmaf(s,w.z,c.z), fmaf(s,w.w,c.w)); }

__device__ __forceinline__ unsigned short f2bfu(float x) {
  unsigned u = __float_as_uint(x);
  return (unsigned short)((u + 0x7FFFu + ((u >> 16) & 1u)) >> 16);  // RNE
}
__device__ __forceinline__ unsigned pack2(float lo, float hi) {
  return (unsigned)f2bfu(lo) | ((unsigned)f2bfu(hi) << 16);
}

struct Params {
  const float *pf, *Wp, *bp, *Wex, *bex, *Wel, *bel, *Wee, *bee, *Wop, *bop,
              *Wch, *bch, *Wsem, *bsem, *Wch2, *bch2;
  float *out_feats, *out_sem, *out_ex, *out_ee;
  float *cf0, *cf1, *Ab, *Bb, *a1, *a2, *part, *part_op;
  unsigned short *W36F;
};

// ---------------------------------------------------------------------------
// gemm_epi phase body (per virtual block vb = (i, jq)); smem arena layout:
//   sEL   : [0, 16384)   32 j-rows x 256 k bf16, XOR-swizzled
//   see   : [16384, 16896)  float[32][4]
//   sexf  : [16896, 17024)  float[32]
// ---------------------------------------------------------------------------
template<int IT>
__device__ __forceinline__ void gemm_epi_body(
    const Params& P, char* smem, int vb, int t)
{
  char*  sEL  = smem;
  float (*see)[4] = reinterpret_cast<float(*)[4]>(smem + 16384);
  float* sexf = reinterpret_cast<float*>(smem + 16896);

  const int i  = vb >> 2;
  const int jq = vb & 3;
  const int w  = t >> 6;
  const int l  = t & 63;
  const float* Wop_it = P.Wop + (size_t)IT * 197632;
  const float* bop_it = P.bop + IT * 256;

  const bool exi = P.out_ex[i] > 0.f;

  // ---- stage EL tile (fp32) + pack bf16 + (IT0) ee
  {
    const int row = t >> 4;        // 0..31
    const int sub = t & 15;
    const int kb  = sub * 16;
    const float* Ap  = P.Ab + i * 256 + kb;
    const float* Bp  = P.Bb + (jq * 32 + row) * 256 + kb;
    const float* blp = P.bel + kb;
    float e[16];
    #pragma unroll
    for (int q = 0; q < 16; q += 4) {
      float4 av = ld4(Ap + q), bv = ld4(Bp + q), lv = ld4(blp + q);
      e[q+0] = fmaxf(av.x + bv.x + lv.x, 0.f);
      e[q+1] = fmaxf(av.y + bv.y + lv.y, 0.f);
      e[q+2] = fmaxf(av.z + bv.z + lv.z, 0.f);
      e[q+3] = fmaxf(av.w + bv.w + lv.w, 0.f);
    }
    if (IT == 0) {
      float s[4] = {0.f, 0.f, 0.f, 0.f};
      #pragma unroll
      for (int tt = 0; tt < 4; ++tt) {
        #pragma unroll
        for (int q = 0; q < 16; q += 4) {
          float4 wv = ld4(P.Wee + tt * 256 + kb + q);
          s[tt] = fmaf(e[q+0], wv.x, s[tt]);
          s[tt] = fmaf(e[q+1], wv.y, s[tt]);
          s[tt] = fmaf(e[q+2], wv.z, s[tt]);
          s[tt] = fmaf(e[q+3], wv.w, s[tt]);
        }
      }
      #pragma unroll
      for (int off = 1; off < 16; off <<= 1) {
        s[0] += __shfl_xor(s[0], off);
        s[1] += __shfl_xor(s[1], off);
        s[2] += __shfl_xor(s[2], off);
        s[3] += __shfl_xor(s[3], off);
      }
      if (sub < 4) {
        const float v = s[sub] + P.bee[sub];
        see[row][sub] = v;
        P.out_ee[(i * 128 + jq * 32 + row) * 4 + sub] = v;
      }
    }
    const int swz = (row & 7) << 4;
    uint4 w0, w1;
    w0.x = pack2(e[0], e[1]);  w0.y = pack2(e[2], e[3]);
    w0.z = pack2(e[4], e[5]);  w0.w = pack2(e[6], e[7]);
    w1.x = pack2(e[8], e[9]);  w1.y = pack2(e[10], e[11]);
    w1.z = pack2(e[12], e[13]); w1.w = pack2(e[14], e[15]);
    *reinterpret_cast<uint4*>(sEL + ((row * 512 + kb * 2)      ^ swz)) = w0;
    *reinterpret_cast<uint4*>(sEL + ((row * 512 + kb * 2 + 16) ^ swz)) = w1;
  }
  if (IT == 1) {
    if (t < 128)
      see[t >> 2][t & 3] = P.out_ee[(i * 128 + jq * 32 + (t >> 2)) * 4 + (t & 3)];
  }
  if (t < 32) sexf[t] = P.out_ex[jq * 32 + t];
  __syncthreads();

  // ---- MFMA: wave w owns cols [w*32, w*32+32) of this iteration's 256
  const int lr = l & 15, lk = l >> 4;
  f32x4 acc[2][2];
  #pragma unroll
  for (int jt = 0; jt < 2; ++jt)
    #pragma unroll
    for (int ct = 0; ct < 2; ++ct)
      acc[jt][ct] = (f32x4){0.f, 0.f, 0.f, 0.f};

  for (int kc = 0; kc < 8; ++kc) {
    const int r0 = lr, r1 = 16 + lr;
    const int kbyte = kc * 64 + lk * 16;
    bf16x8 af0 = *reinterpret_cast<const bf16x8*>(
        sEL + ((r0 * 512 + kbyte) ^ ((r0 & 7) << 4)));
    bf16x8 af1 = *reinterpret_cast<const bf16x8*>(
        sEL + ((r1 * 512 + kbyte) ^ ((r1 & 7) << 4)));
    #pragma unroll
    for (int ct = 0; ct < 2; ++ct) {
      const int fb = (IT * 16 + w * 2 + ct) * 8 + kc;
      bf16x8 bf = *reinterpret_cast<const bf16x8*>(P.W36F + fb * 512 + l * 8);
      acc[0][ct] = __builtin_amdgcn_mfma_f32_16x16x32_bf16(af0, bf, acc[0][ct], 0, 0, 0);
      acc[1][ct] = __builtin_amdgcn_mfma_f32_16x16x32_bf16(af1, bf, acc[1][ct], 0, 0, 0);
    }
  }

  // ---- fused epilogue (fp32 acc, no C round-trip)
  const int c0 = w * 32 + lr, c1 = c0 + 16;
  const float b10 = P.a1[i * 256 + c0] + bop_it[c0];
  const float b11 = P.a1[i * 256 + c1] + bop_it[c1];
  float w40[4], w41[4];
  #pragma unroll
  for (int tt = 0; tt < 4; ++tt) {
    w40[tt] = Wop_it[(768 + tt) * 256 + c0];
    w41[tt] = Wop_it[(768 + tt) * 256 + c1];
  }
  float am0 = 0.f, am1 = 0.f;
  #pragma unroll
  for (int jt = 0; jt < 2; ++jt) {
    #pragma unroll
    for (int q = 0; q < 4; ++q) {
      const int jrow = jt * 16 + lk * 4 + q;
      const int j = jq * 32 + jrow;
      if (exi && (sexf[jrow] > 0.f)) {
        const float e0 = see[jrow][0], e1 = see[jrow][1];
        const float e2 = see[jrow][2], e3 = see[jrow][3];
        const float pb0 = b10 + P.a2[j * 256 + c0] + acc[jt][0][q];
        const float pb1 = b11 + P.a2[j * 256 + c1] + acc[jt][1][q];
        if (e0 > 0.f) { am0 = fmaxf(am0, fmaxf(fmaf(e0, w40[0], pb0), 0.f));
                        am1 = fmaxf(am1, fmaxf(fmaf(e0, w41[0], pb1), 0.f)); }
        if (e1 > 0.f) { am0 = fmaxf(am0, fmaxf(fmaf(e1, w40[1], pb0), 0.f));
                        am1 = fmaxf(am1, fmaxf(fmaf(e1, w41[1], pb1), 0.f)); }
        if (e2 > 0.f) { am0 = fmaxf(am0, fmaxf(fmaf(e2, w40[2], pb0), 0.f));
                        am1 = fmaxf(am1, fmaxf(fmaf(e2, w41[2], pb1), 0.f)); }
        if (e3 > 0.f) { am0 = fmaxf(am0, fmaxf(fmaf(e3, w40[3], pb0), 0.f));
                        am1 = fmaxf(am1, fmaxf(fmaf(e3, w41[3], pb1), 0.f)); }
      }
    }
  }
  am0 = fmaxf(am0, __shfl_xor(am0, 16));
  am0 = fmaxf(am0, __shfl_xor(am0, 32));
  am1 = fmaxf(am1, __shfl_xor(am1, 16));
  am1 = fmaxf(am1, __shfl_xor(am1, 32));
  if (lk == 0) {
    P.part_op[(i * 4 + jq) * 256 + c0] = am0;
    P.part_op[(i * 4 + jq) * 256 + c1] = am1;
  }
}

// ---------------------------------------------------------------------------
// Single cooperative kernel: 256 blocks x 512 thr (1 block/CU, all resident).
// Phases separated by grid.sync(); LDS overlaid in one 34 KB arena.
// ---------------------------------------------------------------------------
__global__ void __launch_bounds__(512) k_all(Params P)
{
  cg::grid_group grid = cg::this_grid();
  const int b = blockIdx.x, t = threadIdx.x;
  __shared__ __align__(16) char smem[34816];

  // ================= phase 1: parent partial matmul + W3 bf16 pack ========
  {
    float* spf = reinterpret_cast<float*>(smem);
    const int kc = b >> 4;               // 16 k-chunks, 16 blocks each
    if (t < 16) spf[t] = P.pf[kc * 16 + t];
    __syncthreads();
    const int col = ((b & 15) * 512 + t) * 4;
    const float* w = P.Wp + (size_t)kc * 16 * 32768 + col;
    float4 acc = make_float4(0.f, 0.f, 0.f, 0.f);
    #pragma unroll
    for (int k = 0; k < 16; ++k)
      acc = fma4(spf[k], ld4(w + (size_t)k * 32768), acc);
    st4(&P.part[kc * 32768 + col], acc);

    // W3 pack: exactly one element per global thread (131072 total)
    const int g = b * 512 + t, fb = g >> 9, e = g & 511;
    const int ct = fb >> 3, kc2 = fb & 7, l = e >> 3, q = e & 7;
    const int c = ct * 16 + (l & 15);
    const int k = kc2 * 32 + (l >> 4) * 8 + q;
    const int it = c >> 8, h = c & 255;
    P.W36F[fb * 512 + e] = f2bfu(P.Wop[(size_t)it * 197632 + (512 + k) * 256 + h]);
  }
  grid.sync();

  // ================= phase 2: stage1 (combine + A/B + a1/a2 it0 + exists) =
  if (b < 128) {
    float* s1_sall = reinterpret_cast<float*>(smem);                  // 1 KB
    float (*s1_red)[2][4][256] =
        reinterpret_cast<float(*)[2][4][256]>(smem + 1024);           // 32 KB
    float* s1_redE = reinterpret_cast<float*>(smem + 33792);          // 16 B
    const int m = b, sel = t >> 8, tt = t & 255;
    if (sel == 0) {
      float v = P.bp[m * 256 + tt];
      #pragma unroll
      for (int q = 0; q < 16; ++q) v += P.part[q * 32768 + m * 256 + tt];
      v = fmaxf(v, 0.f);
      s1_sall[tt] = v;
      P.cf0[m * 256 + tt] = v;
      float p = v * P.Wex[tt];
      #pragma unroll
      for (int off = 32; off > 0; off >>= 1) p += __shfl_xor(p, off);
      if ((tt & 63) == 0) s1_redE[tt >> 6] = p;
    }
    __syncthreads();
    const float* W0 = P.Wel + (sel ? 65536 : 0);
    const float* W1 = P.Wop + (sel ? 65536 : 0);   // iteration-0 W1/W2
    const int hq = (tt & 63) << 2, kg = tt >> 6, k0 = kg * 64;
    float4 acc0 = make_float4(0.f, 0.f, 0.f, 0.f), acc1 = acc0;
    #pragma unroll 4
    for (int k = k0; k < k0 + 64; ++k) {
      const float s = s1_sall[k];
      acc0 = fma4(s, ld4(W0 + k * 256 + hq), acc0);
      acc1 = fma4(s, ld4(W1 + k * 256 + hq), acc1);
    }
    st4(&s1_red[sel][0][kg][hq], acc0);
    st4(&s1_red[sel][1][kg][hq], acc1);
    __syncthreads();
    if (kg < 2) {
      float4 r = add4(add4(ld4(&s1_red[sel][kg][0][hq]), ld4(&s1_red[sel][kg][1][hq])),
                      add4(ld4(&s1_red[sel][kg][2][hq]), ld4(&s1_red[sel][kg][3][hq])));
      float* dst = (kg == 0) ? (sel ? P.Bb : P.Ab) : (sel ? P.a2 : P.a1);
      st4(&dst[m * 256 + hq], r);
    }
    if (t == 0)
      P.out_ex[m] = s1_redE[0] + s1_redE[1] + s1_redE[2] + s1_redE[3] + P.bex[0];
  }
  grid.sync();

  // ================= phase 3: gemm_epi IT=0 (2 virtual blocks per block) ==
  for (int v = 0; v < 2; ++v) {
    if (v) __syncthreads();
    gemm_epi_body<0>(P, smem, b * 2 + v, t);
  }
  grid.sync();

  // ================= phase 4: a12b (combine it0 max + a1/a2 it1) ==========
  if (b < 128) {
    float* a_sall = reinterpret_cast<float*>(smem);                   // 1 KB
    float (*a_red)[4][256] = reinterpret_cast<float(*)[4][256]>(smem + 1024);
    const int m = b, sel = t >> 8, tt = t & 255;
    if (sel == 0) {
      float v = P.part_op[(m * 4 + 0) * 256 + tt];
      v = fmaxf(v, P.part_op[(m * 4 + 1) * 256 + tt]);
      v = fmaxf(v, P.part_op[(m * 4 + 2) * 256 + tt]);
      v = fmaxf(v, P.part_op[(m * 4 + 3) * 256 + tt]);
      a_sall[tt] = v;
      P.cf1[m * 256 + tt] = v;
    }
    __syncthreads();
    const float* W = P.Wop + 197632 + (sel ? 65536 : 0);
    const int hq = (tt & 63) << 2, kg = tt >> 6, k0 = kg * 64;
    float4 acc = make_float4(0.f, 0.f, 0.f, 0.f);
    #pragma unroll 4
    for (int k = k0; k < k0 + 64; ++k)
      acc = fma4(a_sall[k], ld4(W + k * 256 + hq), acc);
    st4(&a_red[sel][kg][hq], acc);
    __syncthreads();
    if (kg == 0) {
      float4 r = add4(add4(ld4(&a_red[sel][0][hq]), ld4(&a_red[sel][1][hq])),
                      add4(ld4(&a_red[sel][2][hq]), ld4(&a_red[sel][3][hq])));
      st4(&((sel ? P.a2 : P.a1)[m * 256 + hq]), r);
    }
  }
  grid.sync();

  // ================= phase 5: gemm_epi IT=1 ===============================
  for (int v = 0; v < 2; ++v) {
    if (v) __syncthreads();
    gemm_epi_body<1>(P, smem, b * 2 + v, t);
  }
  grid.sync();

  // ================= phase 6: final (ch / sem / feats), 8-way K-split =====
  if (b < 128) {
    float* f_sall = reinterpret_cast<float*>(smem);                   // 3 KB
    float* f_sch  = reinterpret_cast<float*>(smem + 3072);            // 1 KB
    float (*f_red)[256] = reinterpret_cast<float(*)[256]>(smem + 4096);   // 8 KB
    float (*f_redS)[64] = reinterpret_cast<float(*)[64]>(smem + 12288);   // 2 KB
    const int m = b, kg = t >> 6, hq = (t & 63) << 2;
    if (t < 256) {
      f_sall[t]       = P.cf0[m * 256 + t];
      f_sall[256 + t] = P.cf1[m * 256 + t];
      float v = P.part_op[(m * 4 + 0) * 256 + t];
      v = fmaxf(v, P.part_op[(m * 4 + 1) * 256 + t]);
      v = fmaxf(v, P.part_op[(m * 4 + 2) * 256 + t]);
      v = fmaxf(v, P.part_op[(m * 4 + 3) * 256 + t]);
      f_sall[512 + t] = v;
    }
    __syncthreads();
    {
      float4 acc = make_float4(0.f, 0.f, 0.f, 0.f);
      const int k0 = kg * 96;
      #pragma unroll 8
      for (int k = k0; k < k0 + 96; ++k)
        acc = fma4(f_sall[k], ld4(P.Wch + k * 256 + hq), acc);
      st4(&f_red[kg][hq], acc);
    }
    __syncthreads();
    if (kg == 0) {
      float4 r = ld4(&f_red[0][hq]);
      #pragma unroll
      for (int g2 = 1; g2 < 8; ++g2) r = add4(r, ld4(&f_red[g2][hq]));
      r = relu4(add4(r, ld4(P.bch + hq)));
      st4(&f_sch[hq], r);
    }
    __syncthreads();
    {
      float4 f = make_float4(0.f, 0.f, 0.f, 0.f);
      const int k0 = kg * 32;
      #pragma unroll 8
      for (int k = k0; k < k0 + 32; ++k)
        f = fma4(f_sch[k], ld4(P.Wch2 + k * 256 + hq), f);
      const int s = t & 63;
      float sv = 0.f;
      if (s < 57) {
        #pragma unroll 8
        for (int k = k0; k < k0 + 32; ++k)
          sv = fmaf(f_sch[k], P.Wsem[k * 57 + s], sv);
      }
      f_redS[kg][s] = sv;
      st4(&f_red[kg][hq], f);   // f_red free: last read was before prev sync
    }
    __syncthreads();
    if (kg == 0) {
      float4 r = ld4(&f_red[0][hq]);
      #pragma unroll
      for (int g2 = 1; g2 < 8; ++g2) r = add4(r, ld4(&f_red[g2][hq]));
      r = relu4(add4(r, ld4(P.bch2 + hq)));
      st4(&P.out_feats[m * 256 + hq], r);
    }
    if (t < 57) {
      float s2 = P.bsem[t];
      #pragma unroll
      for (int g2 = 0; g2 < 8; ++g2) s2 += f_redS[g2][t];
      P.out_sem[m * 57 + t] = s2;
    }
  }
}

// ---------------------------------------------------------------------------
extern "C" void kernel_launch(void* const* d_in, const int* in_sizes, int n_in,
                              void* d_out, int out_size, void* d_ws, size_t ws_size,
                              hipStream_t stream)
{
  Params P;
  P.pf   = (const float*)d_in[0];
  P.Wp   = (const float*)d_in[1];
  P.bp   = (const float*)d_in[2];
  P.Wex  = (const float*)d_in[3];
  P.bex  = (const float*)d_in[4];
  P.Wel  = (const float*)d_in[5];
  P.bel  = (const float*)d_in[6];
  P.Wee  = (const float*)d_in[7];
  P.bee  = (const float*)d_in[8];
  P.Wop  = (const float*)d_in[9];
  P.bop  = (const float*)d_in[10];
  P.Wch  = (const float*)d_in[11];
  P.bch  = (const float*)d_in[12];
  P.Wsem = (const float*)d_in[13];
  P.bsem = (const float*)d_in[14];
  P.Wch2 = (const float*)d_in[15];
  P.bch2 = (const float*)d_in[16];

  // Output layout (fp32): feats | sem | exists | ee
  P.out_feats = (float*)d_out;
  P.out_sem   = P.out_feats + M_ * F_;
  P.out_ex    = P.out_sem + M_ * NSEM_;
  P.out_ee    = P.out_ex + M_;

  // Workspace (floats). part (2 MB, 16 chunks) overlays part_op (time-disjoint).
  float* ws = (float*)d_ws;
  P.cf0 = ws;                       // 32768
  P.cf1 = ws + 32768;               // 32768
  P.Ab  = ws + 65536;               // 32768
  P.Bb  = ws + 98304;               // 32768
  P.a1  = ws + 131072;              // 32768
  P.a2  = ws + 163840;              // 32768
  P.part    = ws + 196608;          // 524288 (dead after phase 2)
  P.part_op = ws + 196608;          // 131072 (overlay)
  P.W36F = (unsigned short*)(ws + 720896);  // 131072 bf16

  void* args[] = { &P };
  hipLaunchCooperativeKernel(k_all, dim3(256), dim3(512), args, 0, stream);
}

// Round 7
// 68.876 us; speedup vs baseline: 3.2684x; 3.2684x over previous
//
#include <hip/hip_runtime.h>
#include <hip/hip_bf16.h>

// Shapes: M=128, H=256, F=256, T=4, I=2, NSEM=57
#define M_ 128
#define H_ 256
#define F_ 256
#define T_ 4
#define NSEM_ 57

typedef __attribute__((ext_vector_type(8))) short bf16x8;
typedef __attribute__((ext_vector_type(4))) float f32x4;

__device__ __forceinline__ float4 ld4(const float* p) { return *reinterpret_cast<const float4*>(p); }
__device__ __forceinline__ void st4(float* p, float4 v) { *reinterpret_cast<float4*>(p) = v; }
__device__ __forceinline__ float4 add4(float4 a, float4 b) { return make_float4(a.x+b.x, a.y+b.y, a.z+b.z, a.w+b.w); }
__device__ __forceinline__ float4 relu4(float4 a) { return make_float4(fmaxf(a.x,0.f), fmaxf(a.y,0.f), fmaxf(a.z,0.f), fmaxf(a.w,0.f)); }
__device__ __forceinline__ float4 fma4(float s, float4 w, float4 c) { return make_float4(fmaf(s,w.x,c.x), fmaf(s,w.y,c.y), fmaf(s,w.z,c.z), fmaf(s,w.w,c.w)); }

__device__ __forceinline__ unsigned short f2bfu(float x) {
  unsigned u = __float_as_uint(x);
  return (unsigned short)((u + 0x7FFFu + ((u >> 16) & 1u)) >> 16);  // RNE
}
__device__ __forceinline__ unsigned pack2(float lo, float hi) {
  return (unsigned)f2bfu(lo) | ((unsigned)f2bfu(hi) << 16);
}

// ---------------------------------------------------------------------------
// K1: parent partial matmul + W-frag bf16 packing (independent work, fused).
// grid 1024 = 32 col-blocks x 32 k-chunks (8 k each), 256 thr (4 blocks/CU).
// Pack: exactly one frag entry per global thread (1024*256 = 262144 =
//       65536 (it0: W3_0, K=256) + 196608 (it1: [W3_1;W2_1;W1_1], K=768)).
// Frag layout: fb = kc*16 + ct; entry e = l*8+q holds W[k= kc*32+(l>>4)*8+q]
//              [h = ct*16+(l&15)].
// ---------------------------------------------------------------------------
__global__ void __launch_bounds__(256) k_parent(
    const float* __restrict__ pf, const float* __restrict__ Wp,
    const float* __restrict__ Wop, float* __restrict__ part,
    unsigned short* __restrict__ W36F, unsigned short* __restrict__ W768F)
{
  const int cb = (blockIdx.x & 31) * 1024 + threadIdx.x * 4;
  const int kc = blockIdx.x >> 5;          // 0..31, 8 k-rows each
  __shared__ float spf[8];
  if (threadIdx.x < 8) spf[threadIdx.x] = pf[kc * 8 + threadIdx.x];
  __syncthreads();
  const float* w = Wp + (size_t)kc * 8 * 32768 + cb;
  float4 acc = make_float4(0.f, 0.f, 0.f, 0.f);
  #pragma unroll
  for (int k = 0; k < 8; ++k)
    acc = fma4(spf[k], ld4(w + (size_t)k * 32768), acc);
  st4(&part[kc * 32768 + cb], acc);

  // ---- W fragment packing
  const int g = blockIdx.x * 256 + threadIdx.x;
  if (g < 65536) {                         // it0: W3_0 only (K=256)
    const int fb = g >> 9, e = g & 511;
    const int kk = fb >> 4, ct = fb & 15;
    const int l = e >> 3, q = e & 7;
    const int k = kk * 32 + ((l >> 4) << 3) + q;       // 0..255
    const int h = ct * 16 + (l & 15);
    W36F[g] = f2bfu(Wop[(size_t)(512 + k) * 256 + h]);
  } else {                                 // it1: [W3_1; W2_1; W1_1] (K=768)
    const int g2 = g - 65536;
    const int fb = g2 >> 9, e = g2 & 511;
    const int kk = fb >> 4, ct = fb & 15;  // kk 0..23
    const int l = e >> 3, q = e & 7;
    const int k = kk * 32 + ((l >> 4) << 3) + q;       // 0..767
    const int h = ct * 16 + (l & 15);
    const int row = (k < 256) ? 512 + k : (k < 512 ? k : k - 512);
    W768F[g2] = f2bfu(Wop[197632 + (size_t)row * 256 + h]);
  }
}

// ---------------------------------------------------------------------------
// K2: stage1 = combine(32 partials) + A/B + a1/a2(it0) + exists + zero cf1/cf2.
// grid 256 = (m, sel), 256 thr.
// ---------------------------------------------------------------------------
__global__ void __launch_bounds__(256) k_stage1(
    const float* __restrict__ part, const float* __restrict__ bp,
    const float* __restrict__ Wel, const float* __restrict__ Wop0,
    const float* __restrict__ Wex, const float* __restrict__ bex,
    float* __restrict__ cf0, float* __restrict__ A, float* __restrict__ B,
    float* __restrict__ a1, float* __restrict__ a2,
    float* __restrict__ cf1, float* __restrict__ cf2,
    float* __restrict__ out_ex)
{
  const int m = blockIdx.x >> 1, sel = blockIdx.x & 1;
  const int t = threadIdx.x;
  __shared__ float sall[256];
  __shared__ float red[2][4][256];
  __shared__ float redE[4];

  // zero atomicMax targets for this call (poison/stale-replay safety)
  (sel ? cf2 : cf1)[m * 256 + t] = 0.f;

  float v = bp[m * 256 + t];
  #pragma unroll 8
  for (int q = 0; q < 32; ++q) v += part[q * 32768 + m * 256 + t];
  v = fmaxf(v, 0.f);
  sall[t] = v;
  if (sel == 0) {
    cf0[m * 256 + t] = v;
    float p = v * Wex[t];
    #pragma unroll
    for (int off = 32; off > 0; off >>= 1) p += __shfl_xor(p, off);
    if ((t & 63) == 0) redE[t >> 6] = p;
  }
  __syncthreads();

  const float* W0 = Wel  + (sel ? 65536 : 0);
  const float* W1 = Wop0 + (sel ? 65536 : 0);
  const int hq = (t & 63) << 2, kg = t >> 6, k0 = kg * 64;
  float4 acc0 = make_float4(0.f, 0.f, 0.f, 0.f), acc1 = acc0;
  #pragma unroll 4
  for (int k = k0; k < k0 + 64; ++k) {
    const float s = sall[k];
    acc0 = fma4(s, ld4(W0 + k * 256 + hq), acc0);
    acc1 = fma4(s, ld4(W1 + k * 256 + hq), acc1);
  }
  st4(&red[0][kg][hq], acc0);
  st4(&red[1][kg][hq], acc1);
  __syncthreads();
  if (kg < 2) {
    float4 r = add4(add4(ld4(&red[kg][0][hq]), ld4(&red[kg][1][hq])),
                    add4(ld4(&red[kg][2][hq]), ld4(&red[kg][3][hq])));
    float* dst = (kg == 0) ? (sel ? B : A) : (sel ? a2 : a1);
    st4(&dst[m * 256 + hq], r);
  }
  if (sel == 0 && t == 0)
    out_ex[m] = redE[0] + redE[1] + redE[2] + redE[3] + bex[0];
}

// ---------------------------------------------------------------------------
// K3: gemm0 = EL tile (fp32) -> ee (exact fp32, written once) + bf16 MFMA
// el@W3_0 (K=256) + fused masked relu-max epilogue -> atomicMax into cf1.
// grid 512 = (i, jq), 512 thr = 8 waves.
// ---------------------------------------------------------------------------
__global__ void __launch_bounds__(512) k_gemm0(
    const float* __restrict__ Arow, const float* __restrict__ Brow,
    const float* __restrict__ bel, const unsigned short* __restrict__ W36F,
    const float* __restrict__ Wee, const float* __restrict__ bee,
    const float* __restrict__ a1, const float* __restrict__ a2,
    const float* __restrict__ Wop0, const float* __restrict__ bop0,
    const float* __restrict__ exlog,
    float* __restrict__ ee_g, float* __restrict__ cf1)
{
  const int i  = blockIdx.x >> 2;
  const int jq = blockIdx.x & 3;
  const int t  = threadIdx.x;
  const int w  = t >> 6;
  const int l  = t & 63;
  __shared__ char sEL[32 * 512];
  __shared__ float see[32][4];
  __shared__ float sexf[32];

  const bool exi = exlog[i] > 0.f;

  {
    const int row = t >> 4;
    const int sub = t & 15;
    const int kb  = sub * 16;
    const float* Ap  = Arow + i * 256 + kb;
    const float* Bp  = Brow + (jq * 32 + row) * 256 + kb;
    const float* blp = bel + kb;
    float e[16];
    #pragma unroll
    for (int q = 0; q < 16; q += 4) {
      float4 av = ld4(Ap + q), bv = ld4(Bp + q), lv = ld4(blp + q);
      e[q+0] = fmaxf(av.x + bv.x + lv.x, 0.f);
      e[q+1] = fmaxf(av.y + bv.y + lv.y, 0.f);
      e[q+2] = fmaxf(av.z + bv.z + lv.z, 0.f);
      e[q+3] = fmaxf(av.w + bv.w + lv.w, 0.f);
    }
    // exact fp32 ee (mask source)
    float s[4] = {0.f, 0.f, 0.f, 0.f};
    #pragma unroll
    for (int tt = 0; tt < 4; ++tt) {
      #pragma unroll
      for (int q = 0; q < 16; q += 4) {
        float4 wv = ld4(Wee + tt * 256 + kb + q);
        s[tt] = fmaf(e[q+0], wv.x, s[tt]);
        s[tt] = fmaf(e[q+1], wv.y, s[tt]);
        s[tt] = fmaf(e[q+2], wv.z, s[tt]);
        s[tt] = fmaf(e[q+3], wv.w, s[tt]);
      }
    }
    #pragma unroll
    for (int off = 1; off < 16; off <<= 1) {
      s[0] += __shfl_xor(s[0], off);
      s[1] += __shfl_xor(s[1], off);
      s[2] += __shfl_xor(s[2], off);
      s[3] += __shfl_xor(s[3], off);
    }
    if (sub < 4) {
      const float v = s[sub] + bee[sub];
      see[row][sub] = v;
      ee_g[(i * 128 + jq * 32 + row) * 4 + sub] = v;
    }
    const int swz = (row & 7) << 4;
    uint4 w0, w1;
    w0.x = pack2(e[0], e[1]);  w0.y = pack2(e[2], e[3]);
    w0.z = pack2(e[4], e[5]);  w0.w = pack2(e[6], e[7]);
    w1.x = pack2(e[8], e[9]);  w1.y = pack2(e[10], e[11]);
    w1.z = pack2(e[12], e[13]); w1.w = pack2(e[14], e[15]);
    *reinterpret_cast<uint4*>(sEL + ((row * 512 + kb * 2)      ^ swz)) = w0;
    *reinterpret_cast<uint4*>(sEL + ((row * 512 + kb * 2 + 16) ^ swz)) = w1;
  }
  if (t < 32) sexf[t] = exlog[jq * 32 + t];
  __syncthreads();

  const int lr = l & 15, lk = l >> 4;
  f32x4 acc[2][2];
  #pragma unroll
  for (int jt = 0; jt < 2; ++jt)
    #pragma unroll
    for (int ct = 0; ct < 2; ++ct)
      acc[jt][ct] = (f32x4){0.f, 0.f, 0.f, 0.f};

  for (int kc = 0; kc < 8; ++kc) {
    const int kbyte = kc * 64 + lk * 16;
    bf16x8 af0 = *reinterpret_cast<const bf16x8*>(
        sEL + ((lr * 512 + kbyte) ^ ((lr & 7) << 4)));
    bf16x8 af1 = *reinterpret_cast<const bf16x8*>(
        sEL + (((16 + lr) * 512 + kbyte) ^ ((lr & 7) << 4)));
    #pragma unroll
    for (int ct = 0; ct < 2; ++ct) {
      const int fb = kc * 16 + (w * 2 + ct);
      bf16x8 bf = *reinterpret_cast<const bf16x8*>(W36F + fb * 512 + l * 8);
      acc[0][ct] = __builtin_amdgcn_mfma_f32_16x16x32_bf16(af0, bf, acc[0][ct], 0, 0, 0);
      acc[1][ct] = __builtin_amdgcn_mfma_f32_16x16x32_bf16(af1, bf, acc[1][ct], 0, 0, 0);
    }
  }

  // epilogue: pre = a1_i + a2_j + el@W3 + ee*W4 + b; relu; mask; max over (j,t)
  const int c0 = w * 32 + lr, c1 = c0 + 16;
  const float b10 = a1[i * 256 + c0] + bop0[c0];
  const float b11 = a1[i * 256 + c1] + bop0[c1];
  float w40[4], w41[4];
  #pragma unroll
  for (int tt = 0; tt < 4; ++tt) {
    w40[tt] = Wop0[(768 + tt) * 256 + c0];
    w41[tt] = Wop0[(768 + tt) * 256 + c1];
  }
  float am0 = 0.f, am1 = 0.f;
  #pragma unroll
  for (int jt = 0; jt < 2; ++jt) {
    #pragma unroll
    for (int q = 0; q < 4; ++q) {
      const int jrow = jt * 16 + lk * 4 + q;
      const int j = jq * 32 + jrow;
      if (exi && (sexf[jrow] > 0.f)) {
        const float e0 = see[jrow][0], e1 = see[jrow][1];
        const float e2 = see[jrow][2], e3 = see[jrow][3];
        const float pb0 = b10 + a2[j * 256 + c0] + acc[jt][0][q];
        const float pb1 = b11 + a2[j * 256 + c1] + acc[jt][1][q];
        if (e0 > 0.f) { am0 = fmaxf(am0, fmaxf(fmaf(e0, w40[0], pb0), 0.f));
                        am1 = fmaxf(am1, fmaxf(fmaf(e0, w41[0], pb1), 0.f)); }
        if (e1 > 0.f) { am0 = fmaxf(am0, fmaxf(fmaf(e1, w40[1], pb0), 0.f));
                        am1 = fmaxf(am1, fmaxf(fmaf(e1, w41[1], pb1), 0.f)); }
        if (e2 > 0.f) { am0 = fmaxf(am0, fmaxf(fmaf(e2, w40[2], pb0), 0.f));
                        am1 = fmaxf(am1, fmaxf(fmaf(e2, w41[2], pb1), 0.f)); }
        if (e3 > 0.f) { am0 = fmaxf(am0, fmaxf(fmaf(e3, w40[3], pb0), 0.f));
                        am1 = fmaxf(am1, fmaxf(fmaf(e3, w41[3], pb1), 0.f)); }
      }
    }
  }
  am0 = fmaxf(am0, __shfl_xor(am0, 16));
  am0 = fmaxf(am0, __shfl_xor(am0, 32));
  am1 = fmaxf(am1, __shfl_xor(am1, 16));
  am1 = fmaxf(am1, __shfl_xor(am1, 32));
  if (lk == 0) {  // values >= 0: float bits monotone as uint; max is exact
    atomicMax((unsigned int*)&cf1[i * 256 + c0], __float_as_uint(am0));
    atomicMax((unsigned int*)&cf1[i * 256 + c1], __float_as_uint(am1));
  }
}

// ---------------------------------------------------------------------------
// K4: gemm1 = K=768 MFMA: [el_ij | cf1_j | cf1_i] @ [W3_1; W2_1; W1_1] +
// masked relu-max epilogue -> atomicMax into cf2. No a1/a2 precompute needed.
// grid 512 = (i, jq), 512 thr. LDS 32 x 768 bf16 (48 KB), XOR-swizzled.
// ---------------------------------------------------------------------------
__global__ void __launch_bounds__(512) k_gemm1(
    const float* __restrict__ Arow, const float* __restrict__ Brow,
    const float* __restrict__ bel, const unsigned short* __restrict__ W768F,
    const float* __restrict__ cf1,
    const float* __restrict__ Wop1, const float* __restrict__ bop1,
    const float* __restrict__ exlog, const float* __restrict__ ee_g,
    float* __restrict__ cf2)
{
  const int i  = blockIdx.x >> 2;
  const int jq = blockIdx.x & 3;
  const int t  = threadIdx.x;
  const int w  = t >> 6;
  const int l  = t & 63;
  __shared__ char sEL[32 * 1536];
  __shared__ float see[32][4];
  __shared__ float sexf[32];

  const bool exi = exlog[i] > 0.f;

  {
    const int row = t >> 4;
    const int sub = t & 15;
    const int kb  = sub * 16;
    const int swz = (row & 7) << 4;
    // seg 0: el (cols 0..255)
    {
      const float* Ap  = Arow + i * 256 + kb;
      const float* Bp  = Brow + (jq * 32 + row) * 256 + kb;
      const float* blp = bel + kb;
      float e[16];
      #pragma unroll
      for (int q = 0; q < 16; q += 4) {
        float4 av = ld4(Ap + q), bv = ld4(Bp + q), lv = ld4(blp + q);
        e[q+0] = fmaxf(av.x + bv.x + lv.x, 0.f);
        e[q+1] = fmaxf(av.y + bv.y + lv.y, 0.f);
        e[q+2] = fmaxf(av.z + bv.z + lv.z, 0.f);
        e[q+3] = fmaxf(av.w + bv.w + lv.w, 0.f);
      }
      uint4 w0, w1;
      w0.x = pack2(e[0], e[1]);  w0.y = pack2(e[2], e[3]);
      w0.z = pack2(e[4], e[5]);  w0.w = pack2(e[6], e[7]);
      w1.x = pack2(e[8], e[9]);  w1.y = pack2(e[10], e[11]);
      w1.z = pack2(e[12], e[13]); w1.w = pack2(e[14], e[15]);
      *reinterpret_cast<uint4*>(sEL + ((row * 1536 + kb * 2)      ^ swz)) = w0;
      *reinterpret_cast<uint4*>(sEL + ((row * 1536 + kb * 2 + 16) ^ swz)) = w1;
    }
    // seg 1: cf1_j (cols 256..511)
    {
      const float* cj = cf1 + (jq * 32 + row) * 256 + kb;
      float4 v0 = ld4(cj), v1 = ld4(cj + 4), v2 = ld4(cj + 8), v3 = ld4(cj + 12);
      uint4 w0, w1;
      w0.x = pack2(v0.x, v0.y); w0.y = pack2(v0.z, v0.w);
      w0.z = pack2(v1.x, v1.y); w0.w = pack2(v1.z, v1.w);
      w1.x = pack2(v2.x, v2.y); w1.y = pack2(v2.z, v2.w);
      w1.z = pack2(v3.x, v3.y); w1.w = pack2(v3.z, v3.w);
      *reinterpret_cast<uint4*>(sEL + ((row * 1536 + 512 + kb * 2)      ^ swz)) = w0;
      *reinterpret_cast<uint4*>(sEL + ((row * 1536 + 512 + kb * 2 + 16) ^ swz)) = w1;
    }
    // seg 2: cf1_i (cols 512..767), identical for all rows
    {
      const float* ci = cf1 + i * 256 + kb;
      float4 v0 = ld4(ci), v1 = ld4(ci + 4), v2 = ld4(ci + 8), v3 = ld4(ci + 12);
      uint4 w0, w1;
      w0.x = pack2(v0.x, v0.y); w0.y = pack2(v0.z, v0.w);
      w0.z = pack2(v1.x, v1.y); w0.w = pack2(v1.z, v1.w);
      w1.x = pack2(v2.x, v2.y); w1.y = pack2(v2.z, v2.w);
      w1.z = pack2(v3.x, v3.y); w1.w = pack2(v3.z, v3.w);
      *reinterpret_cast<uint4*>(sEL + ((row * 1536 + 1024 + kb * 2)      ^ swz)) = w0;
      *reinterpret_cast<uint4*>(sEL + ((row * 1536 + 1024 + kb * 2 + 16) ^ swz)) = w1;
    }
  }
  if (t < 128)
    see[t >> 2][t & 3] = ee_g[(i * 128 + jq * 32 + (t >> 2)) * 4 + (t & 3)];
  if (t < 32) sexf[t] = exlog[jq * 32 + t];
  __syncthreads();

  const int lr = l & 15, lk = l >> 4;
  f32x4 acc[2][2];
  #pragma unroll
  for (int jt = 0; jt < 2; ++jt)
    #pragma unroll
    for (int ct = 0; ct < 2; ++ct)
      acc[jt][ct] = (f32x4){0.f, 0.f, 0.f, 0.f};

  for (int kc = 0; kc < 24; ++kc) {
    const int kbyte = kc * 64 + lk * 16;
    bf16x8 af0 = *reinterpret_cast<const bf16x8*>(
        sEL + ((lr * 1536 + kbyte) ^ ((lr & 7) << 4)));
    bf16x8 af1 = *reinterpret_cast<const bf16x8*>(
        sEL + (((16 + lr) * 1536 + kbyte) ^ ((lr & 7) << 4)));
    #pragma unroll
    for (int ct = 0; ct < 2; ++ct) {
      const int fb = kc * 16 + (w * 2 + ct);
      bf16x8 bf = *reinterpret_cast<const bf16x8*>(W768F + fb * 512 + l * 8);
      acc[0][ct] = __builtin_amdgcn_mfma_f32_16x16x32_bf16(af0, bf, acc[0][ct], 0, 0, 0);
      acc[1][ct] = __builtin_amdgcn_mfma_f32_16x16x32_bf16(af1, bf, acc[1][ct], 0, 0, 0);
    }
  }

  // epilogue: pre = acc (has a1+a2+el@W3) + ee*W4 + b
  const int c0 = w * 32 + lr, c1 = c0 + 16;
  const float b10 = bop1[c0];
  const float b11 = bop1[c1];
  float w40[4], w41[4];
  #pragma unroll
  for (int tt = 0; tt < 4; ++tt) {
    w40[tt] = Wop1[(768 + tt) * 256 + c0];
    w41[tt] = Wop1[(768 + tt) * 256 + c1];
  }
  float am0 = 0.f, am1 = 0.f;
  #pragma unroll
  for (int jt = 0; jt < 2; ++jt) {
    #pragma unroll
    for (int q = 0; q < 4; ++q) {
      const int jrow = jt * 16 + lk * 4 + q;
      if (exi && (sexf[jrow] > 0.f)) {
        const float e0 = see[jrow][0], e1 = see[jrow][1];
        const float e2 = see[jrow][2], e3 = see[jrow][3];
        const float pb0 = b10 + acc[jt][0][q];
        const float pb1 = b11 + acc[jt][1][q];
        if (e0 > 0.f) { am0 = fmaxf(am0, fmaxf(fmaf(e0, w40[0], pb0), 0.f));
                        am1 = fmaxf(am1, fmaxf(fmaf(e0, w41[0], pb1), 0.f)); }
        if (e1 > 0.f) { am0 = fmaxf(am0, fmaxf(fmaf(e1, w40[1], pb0), 0.f));
                        am1 = fmaxf(am1, fmaxf(fmaf(e1, w41[1], pb1), 0.f)); }
        if (e2 > 0.f) { am0 = fmaxf(am0, fmaxf(fmaf(e2, w40[2], pb0), 0.f));
                        am1 = fmaxf(am1, fmaxf(fmaf(e2, w41[2], pb1), 0.f)); }
        if (e3 > 0.f) { am0 = fmaxf(am0, fmaxf(fmaf(e3, w40[3], pb0), 0.f));
                        am1 = fmaxf(am1, fmaxf(fmaf(e3, w41[3], pb1), 0.f)); }
      }
    }
  }
  am0 = fmaxf(am0, __shfl_xor(am0, 16));
  am0 = fmaxf(am0, __shfl_xor(am0, 32));
  am1 = fmaxf(am1, __shfl_xor(am1, 16));
  am1 = fmaxf(am1, __shfl_xor(am1, 32));
  if (lk == 0) {
    atomicMax((unsigned int*)&cf2[i * 256 + c0], __float_as_uint(am0));
    atomicMax((unsigned int*)&cf2[i * 256 + c1], __float_as_uint(am1));
  }
}

// ---------------------------------------------------------------------------
// K5: ch/sem/feats from [cf0|cf1|cf2]. grid 128 (m) x 256 thr.
// ---------------------------------------------------------------------------
__global__ void __launch_bounds__(256) k_final(
    const float* __restrict__ cf0, const float* __restrict__ cf1,
    const float* __restrict__ cf2,
    const float* __restrict__ Wch, const float* __restrict__ bch,
    const float* __restrict__ Wsem, const float* __restrict__ bsem,
    const float* __restrict__ Wch2, const float* __restrict__ bch2,
    float* __restrict__ out_feats, float* __restrict__ out_sem)
{
  const int m  = blockIdx.x;
  const int t  = threadIdx.x;
  const int hq = (t & 63) << 2;
  const int kg = t >> 6;
  __shared__ float sall[768];
  __shared__ float sch[256];
  __shared__ float red[4][256];
  __shared__ float redS[4][64];

  sall[t]       = cf0[m * 256 + t];
  sall[256 + t] = cf1[m * 256 + t];
  sall[512 + t] = cf2[m * 256 + t];
  __syncthreads();

  {
    float4 acc = make_float4(0.f, 0.f, 0.f, 0.f);
    const int k0 = kg * 192;
    #pragma unroll 8
    for (int k = k0; k < k0 + 192; ++k)
      acc = fma4(sall[k], ld4(Wch + k * 256 + hq), acc);
    st4(&red[kg][hq], acc);
  }
  __syncthreads();
  if (kg == 0) {
    float4 r = add4(add4(ld4(&red[0][hq]), ld4(&red[1][hq])),
                    add4(ld4(&red[2][hq]), ld4(&red[3][hq])));
    r = relu4(add4(r, ld4(bch + hq)));
    st4(&sch[hq], r);
  }
  __syncthreads();

  {
    float4 f = make_float4(0.f, 0.f, 0.f, 0.f);
    const int k0 = kg * 64;
    #pragma unroll 8
    for (int k = k0; k < k0 + 64; ++k)
      f = fma4(sch[k], ld4(Wch2 + k * 256 + hq), f);
    const int s = t & 63;
    float sv = 0.f;
    if (s < 57) {
      #pragma unroll 8
      for (int k = k0; k < k0 + 64; ++k)
        sv = fmaf(sch[k], Wsem[k * 57 + s], sv);
    }
    redS[kg][s] = sv;
    __syncthreads();
    st4(&red[kg][hq], f);
  }
  __syncthreads();
  if (kg == 0) {
    float4 r = add4(add4(ld4(&red[0][hq]), ld4(&red[1][hq])),
                    add4(ld4(&red[2][hq]), ld4(&red[3][hq])));
    r = relu4(add4(r, ld4(bch2 + hq)));
    st4(&out_feats[m * 256 + hq], r);
    const int s = t & 63;
    if (s < 57)
      out_sem[m * 57 + s] = redS[0][s] + redS[1][s] + redS[2][s] + redS[3][s]
                          + bsem[s];
  }
}

// ---------------------------------------------------------------------------
extern "C" void kernel_launch(void* const* d_in, const int* in_sizes, int n_in,
                              void* d_out, int out_size, void* d_ws, size_t ws_size,
                              hipStream_t stream)
{
  const float* pf   = (const float*)d_in[0];
  const float* Wp   = (const float*)d_in[1];
  const float* bp   = (const float*)d_in[2];
  const float* Wex  = (const float*)d_in[3];
  const float* bex  = (const float*)d_in[4];
  const float* Wel  = (const float*)d_in[5];
  const float* bel  = (const float*)d_in[6];
  const float* Wee  = (const float*)d_in[7];
  const float* bee  = (const float*)d_in[8];
  const float* Wop  = (const float*)d_in[9];
  const float* bop  = (const float*)d_in[10];
  const float* Wch  = (const float*)d_in[11];
  const float* bch  = (const float*)d_in[12];
  const float* Wsem = (const float*)d_in[13];
  const float* bsem = (const float*)d_in[14];
  const float* Wch2 = (const float*)d_in[15];
  const float* bch2 = (const float*)d_in[16];

  // Output layout (fp32): feats | sem | exists | ee
  float* out_feats = (float*)d_out;
  float* out_sem   = out_feats + M_ * F_;
  float* out_ex    = out_sem + M_ * NSEM_;
  float* out_ee    = out_ex + M_;

  // Workspace (floats)
  float* ws = (float*)d_ws;
  float* cf0 = ws;                     // 32768
  float* cf1 = ws + 32768;             // 32768 (atomicMax target, zeroed in stage1)
  float* cf2 = ws + 65536;             // 32768 (atomicMax target, zeroed in stage1)
  float* Ab  = ws + 98304;             // 32768
  float* Bb  = ws + 131072;            // 32768
  float* a1  = ws + 163840;            // 32768
  float* a2  = ws + 196608;            // 32768
  float* part = ws + 229376;           // 32*32768 = 1048576 floats (4 MB)
  unsigned short* W36F  = (unsigned short*)(ws + 1277952);  // 65536 bf16
  unsigned short* W768F = (unsigned short*)(ws + 1310720);  // 196608 bf16

  const float* Wop0 = Wop;               // iteration 0 block (772*256 floats)
  const float* Wop1 = Wop + 197632;      // iteration 1 block

  k_parent<<<1024, 256, 0, stream>>>(pf, Wp, Wop, part, W36F, W768F);
  k_stage1<<<256, 256, 0, stream>>>(part, bp, Wel, Wop0, Wex, bex,
                                    cf0, Ab, Bb, a1, a2, cf1, cf2, out_ex);
  k_gemm0<<<512, 512, 0, stream>>>(Ab, Bb, bel, W36F, Wee, bee,
                                   a1, a2, Wop0, bop, out_ex, out_ee, cf1);
  k_gemm1<<<512, 512, 0, stream>>>(Ab, Bb, bel, W768F, cf1,
                                   Wop1, bop + 256, out_ex, out_ee, cf2);
  k_final<<<128, 256, 0, stream>>>(cf0, cf1, cf2, Wch, bch, Wsem, bsem,
                                   Wch2, bch2, out_feats, out_sem);
}

// Round 8
// 65.438 us; speedup vs baseline: 3.4402x; 1.0526x over previous
//
#include <hip/hip_runtime.h>
#include <hip/hip_bf16.h>

// Shapes: M=128, H=256, F=256, T=4, I=2, NSEM=57
#define M_ 128
#define H_ 256
#define F_ 256
#define T_ 4
#define NSEM_ 57

typedef __attribute__((ext_vector_type(8))) short bf16x8;
typedef __attribute__((ext_vector_type(4))) float f32x4;

__device__ __forceinline__ float4 ld4(const float* p) { return *reinterpret_cast<const float4*>(p); }
__device__ __forceinline__ void st4(float* p, float4 v) { *reinterpret_cast<float4*>(p) = v; }
__device__ __forceinline__ float4 add4(float4 a, float4 b) { return make_float4(a.x+b.x, a.y+b.y, a.z+b.z, a.w+b.w); }
__device__ __forceinline__ float4 relu4(float4 a) { return make_float4(fmaxf(a.x,0.f), fmaxf(a.y,0.f), fmaxf(a.z,0.f), fmaxf(a.w,0.f)); }
__device__ __forceinline__ float4 fma4(float s, float4 w, float4 c) { return make_float4(fmaf(s,w.x,c.x), fmaf(s,w.y,c.y), fmaf(s,w.z,c.z), fmaf(s,w.w,c.w)); }

__device__ __forceinline__ unsigned short f2bfu(float x) {
  unsigned u = __float_as_uint(x);
  return (unsigned short)((u + 0x7FFFu + ((u >> 16) & 1u)) >> 16);  // RNE
}
__device__ __forceinline__ unsigned pack2(float lo, float hi) {
  return (unsigned)f2bfu(lo) | ((unsigned)f2bfu(hi) << 16);
}

// ---------------------------------------------------------------------------
// K1: parent partial matmul + W-frag bf16 packing.
// grid 1024 = 32 col-blocks x 32 k-chunks (8 k each), 256 thr.
// W-pack via LDS-staged 16x16 tile: coalesced 64B global reads (was 16x
// amplified scattered 4B reads), padded LDS kills bank conflicts.
// Block b packs half-frag: fb = b>>1, entries e = (b&1)*256 + t.
// ---------------------------------------------------------------------------
__global__ void __launch_bounds__(256) k_parent(
    const float* __restrict__ pf, const float* __restrict__ Wp,
    const float* __restrict__ Wop, float* __restrict__ part,
    unsigned short* __restrict__ W36F, unsigned short* __restrict__ W768F)
{
  const int t = threadIdx.x;
  __shared__ float spf[8];
  __shared__ float tile[16][17];

  // ---- issue W-tile reads first (independent; overlap with GEMV)
  // fb_global = b>>1 in [0, 512): [0,128) -> W36F (it0), [128,512) -> W768F.
  const int fbg = blockIdx.x >> 1;
  const int half = blockIdx.x & 1;
  const bool it0 = fbg < 128;
  const int fb = it0 ? fbg : fbg - 128;
  const int kk = fb >> 4, ct = fb & 15;
  const int base_k = kk * 32 + half * 16;
  int row_base;
  if (it0) row_base = 512 + base_k;                 // W3_0
  else row_base = (base_k < 256) ? 512 + base_k     // W3_1
                : (base_k < 512 ? base_k : base_k - 512);  // W2_1 / W1_1
  const float* wsrc = Wop + (it0 ? 0 : 197632);
  {
    const int r = t >> 4, c = t & 15;
    tile[r][c] = wsrc[(size_t)(row_base + r) * 256 + ct * 16 + c];
  }

  // ---- parent GEMV partial
  const int cb = (blockIdx.x & 31) * 1024 + t * 4;
  const int kc = blockIdx.x >> 5;
  if (t < 8) spf[t] = pf[kc * 8 + t];
  __syncthreads();
  const float* w = Wp + (size_t)kc * 8 * 32768 + cb;
  float4 acc = make_float4(0.f, 0.f, 0.f, 0.f);
  #pragma unroll
  for (int k = 0; k < 8; ++k)
    acc = fma4(spf[k], ld4(w + (size_t)k * 32768), acc);
  st4(&part[kc * 32768 + cb], acc);

  // ---- pack from LDS tile (conflict-free: addr = k_local*17 + h_local)
  {
    const int k_local = ((t >> 7) << 3) + (t & 7);
    const int h_local = (t >> 3) & 15;
    const int e = half * 256 + t;
    unsigned short v = f2bfu(tile[k_local][h_local]);
    if (it0) W36F[fb * 512 + e] = v;
    else     W768F[fb * 512 + e] = v;
  }
}

// ---------------------------------------------------------------------------
// K2: stage1 = combine(32 partials) + A/B + a1/a2(it0) + exists + zero cf1/cf2.
// grid 256 = (m, sel), 256 thr. Full unroll: 32 part loads in flight.
// ---------------------------------------------------------------------------
__global__ void __launch_bounds__(256) k_stage1(
    const float* __restrict__ part, const float* __restrict__ bp,
    const float* __restrict__ Wel, const float* __restrict__ Wop0,
    const float* __restrict__ Wex, const float* __restrict__ bex,
    float* __restrict__ cf0, float* __restrict__ A, float* __restrict__ B,
    float* __restrict__ a1, float* __restrict__ a2,
    float* __restrict__ cf1, float* __restrict__ cf2,
    float* __restrict__ out_ex)
{
  const int m = blockIdx.x >> 1, sel = blockIdx.x & 1;
  const int t = threadIdx.x;
  __shared__ float sall[256];
  __shared__ float red[2][4][256];
  __shared__ float redE[4];

  // zero atomicMax targets for this call (poison/stale-replay safety)
  (sel ? cf2 : cf1)[m * 256 + t] = 0.f;

  float pv[32];
  #pragma unroll
  for (int q = 0; q < 32; ++q) pv[q] = part[q * 32768 + m * 256 + t];
  float v = bp[m * 256 + t];
  #pragma unroll
  for (int q = 0; q < 32; ++q) v += pv[q];
  v = fmaxf(v, 0.f);
  sall[t] = v;
  if (sel == 0) {
    cf0[m * 256 + t] = v;
    float p = v * Wex[t];
    #pragma unroll
    for (int off = 32; off > 0; off >>= 1) p += __shfl_xor(p, off);
    if ((t & 63) == 0) redE[t >> 6] = p;
  }
  __syncthreads();

  const float* W0 = Wel  + (sel ? 65536 : 0);
  const float* W1 = Wop0 + (sel ? 65536 : 0);
  const int hq = (t & 63) << 2, kg = t >> 6, k0 = kg * 64;
  float4 acc0 = make_float4(0.f, 0.f, 0.f, 0.f), acc1 = acc0;
  #pragma unroll 8
  for (int k = k0; k < k0 + 64; ++k) {
    const float s = sall[k];
    acc0 = fma4(s, ld4(W0 + k * 256 + hq), acc0);
    acc1 = fma4(s, ld4(W1 + k * 256 + hq), acc1);
  }
  st4(&red[0][kg][hq], acc0);
  st4(&red[1][kg][hq], acc1);
  __syncthreads();
  if (kg < 2) {
    float4 r = add4(add4(ld4(&red[kg][0][hq]), ld4(&red[kg][1][hq])),
                    add4(ld4(&red[kg][2][hq]), ld4(&red[kg][3][hq])));
    float* dst = (kg == 0) ? (sel ? B : A) : (sel ? a2 : a1);
    st4(&dst[m * 256 + hq], r);
  }
  if (sel == 0 && t == 0)
    out_ex[m] = redE[0] + redE[1] + redE[2] + redE[3] + bex[0];
}

// ---------------------------------------------------------------------------
// K3: gemm0 = EL tile (fp32) -> ee (fp32, written once) + bf16 MFMA el@W3_0
// (K=256, depth-1 pipelined frag loads) + fused masked relu-max epilogue
// (operands hoisted above barrier) -> atomicMax into cf1.
// grid 512 = (i, jq), 512 thr = 8 waves.
// ---------------------------------------------------------------------------
__global__ void __launch_bounds__(512) k_gemm0(
    const float* __restrict__ Arow, const float* __restrict__ Brow,
    const float* __restrict__ bel, const unsigned short* __restrict__ W36F,
    const float* __restrict__ Wee, const float* __restrict__ bee,
    const float* __restrict__ a1, const float* __restrict__ a2,
    const float* __restrict__ Wop0, const float* __restrict__ bop0,
    const float* __restrict__ exlog,
    float* __restrict__ ee_g, float* __restrict__ cf1)
{
  const int i  = blockIdx.x >> 2;
  const int jq = blockIdx.x & 3;
  const int t  = threadIdx.x;
  const int w  = t >> 6;
  const int l  = t & 63;
  __shared__ char sEL[32 * 512];
  __shared__ float see[32][4];
  __shared__ float sexf[32];

  const bool exi = exlog[i] > 0.f;
  const int lr = l & 15, lk = l >> 4;

  // ---- hoisted epilogue operands (issue early, consumed after MFMA)
  const int c0 = w * 32 + lr, c1 = c0 + 16;
  const float b10 = a1[i * 256 + c0] + bop0[c0];
  const float b11 = a1[i * 256 + c1] + bop0[c1];
  float w40[4], w41[4], a2v0[8], a2v1[8];
  #pragma unroll
  for (int tt = 0; tt < 4; ++tt) {
    w40[tt] = Wop0[(768 + tt) * 256 + c0];
    w41[tt] = Wop0[(768 + tt) * 256 + c1];
  }
  #pragma unroll
  for (int jt = 0; jt < 2; ++jt)
    #pragma unroll
    for (int q = 0; q < 4; ++q) {
      const int j = jq * 32 + jt * 16 + lk * 4 + q;
      a2v0[jt * 4 + q] = a2[j * 256 + c0];
      a2v1[jt * 4 + q] = a2[j * 256 + c1];
    }

  // ---- stage EL tile (fp32) + ee + pack bf16
  {
    const int row = t >> 4;
    const int sub = t & 15;
    const int kb  = sub * 16;
    const float* Ap  = Arow + i * 256 + kb;
    const float* Bp  = Brow + (jq * 32 + row) * 256 + kb;
    const float* blp = bel + kb;
    float e[16];
    #pragma unroll
    for (int q = 0; q < 16; q += 4) {
      float4 av = ld4(Ap + q), bv = ld4(Bp + q), lv = ld4(blp + q);
      e[q+0] = fmaxf(av.x + bv.x + lv.x, 0.f);
      e[q+1] = fmaxf(av.y + bv.y + lv.y, 0.f);
      e[q+2] = fmaxf(av.z + bv.z + lv.z, 0.f);
      e[q+3] = fmaxf(av.w + bv.w + lv.w, 0.f);
    }
    float s[4] = {0.f, 0.f, 0.f, 0.f};
    #pragma unroll
    for (int tt = 0; tt < 4; ++tt) {
      #pragma unroll
      for (int q = 0; q < 16; q += 4) {
        float4 wv = ld4(Wee + tt * 256 + kb + q);
        s[tt] = fmaf(e[q+0], wv.x, s[tt]);
        s[tt] = fmaf(e[q+1], wv.y, s[tt]);
        s[tt] = fmaf(e[q+2], wv.z, s[tt]);
        s[tt] = fmaf(e[q+3], wv.w, s[tt]);
      }
    }
    #pragma unroll
    for (int off = 1; off < 16; off <<= 1) {
      s[0] += __shfl_xor(s[0], off);
      s[1] += __shfl_xor(s[1], off);
      s[2] += __shfl_xor(s[2], off);
      s[3] += __shfl_xor(s[3], off);
    }
    if (sub < 4) {
      const float v = s[sub] + bee[sub];
      see[row][sub] = v;
      ee_g[(i * 128 + jq * 32 + row) * 4 + sub] = v;
    }
    const int swz = (row & 7) << 4;
    uint4 w0, w1;
    w0.x = pack2(e[0], e[1]);  w0.y = pack2(e[2], e[3]);
    w0.z = pack2(e[4], e[5]);  w0.w = pack2(e[6], e[7]);
    w1.x = pack2(e[8], e[9]);  w1.y = pack2(e[10], e[11]);
    w1.z = pack2(e[12], e[13]); w1.w = pack2(e[14], e[15]);
    *reinterpret_cast<uint4*>(sEL + ((row * 512 + kb * 2)      ^ swz)) = w0;
    *reinterpret_cast<uint4*>(sEL + ((row * 512 + kb * 2 + 16) ^ swz)) = w1;
  }
  if (t < 32) sexf[t] = exlog[jq * 32 + t];
  __syncthreads();

  // ---- MFMA: depth-1 pipelined loads (frags from L2, A from LDS)
  f32x4 acc[2][2];
  #pragma unroll
  for (int jt = 0; jt < 2; ++jt)
    #pragma unroll
    for (int ct = 0; ct < 2; ++ct)
      acc[jt][ct] = (f32x4){0.f, 0.f, 0.f, 0.f};

  const int swz0 = (lr & 7) << 4;
  bf16x8 cb0 = *reinterpret_cast<const bf16x8*>(W36F + (0 * 16 + w * 2 + 0) * 512 + l * 8);
  bf16x8 cb1 = *reinterpret_cast<const bf16x8*>(W36F + (0 * 16 + w * 2 + 1) * 512 + l * 8);
  bf16x8 ca0 = *reinterpret_cast<const bf16x8*>(sEL + ((lr * 512 + lk * 16) ^ swz0));
  bf16x8 ca1 = *reinterpret_cast<const bf16x8*>(sEL + (((16 + lr) * 512 + lk * 16) ^ swz0));
  #pragma unroll
  for (int kc = 0; kc < 8; ++kc) {
    bf16x8 nb0, nb1, na0, na1;
    if (kc < 7) {
      const int kbyte = (kc + 1) * 64 + lk * 16;
      nb0 = *reinterpret_cast<const bf16x8*>(W36F + ((kc + 1) * 16 + w * 2 + 0) * 512 + l * 8);
      nb1 = *reinterpret_cast<const bf16x8*>(W36F + ((kc + 1) * 16 + w * 2 + 1) * 512 + l * 8);
      na0 = *reinterpret_cast<const bf16x8*>(sEL + ((lr * 512 + kbyte) ^ swz0));
      na1 = *reinterpret_cast<const bf16x8*>(sEL + (((16 + lr) * 512 + kbyte) ^ swz0));
    }
    acc[0][0] = __builtin_amdgcn_mfma_f32_16x16x32_bf16(ca0, cb0, acc[0][0], 0, 0, 0);
    acc[1][0] = __builtin_amdgcn_mfma_f32_16x16x32_bf16(ca1, cb0, acc[1][0], 0, 0, 0);
    acc[0][1] = __builtin_amdgcn_mfma_f32_16x16x32_bf16(ca0, cb1, acc[0][1], 0, 0, 0);
    acc[1][1] = __builtin_amdgcn_mfma_f32_16x16x32_bf16(ca1, cb1, acc[1][1], 0, 0, 0);
    if (kc < 7) { cb0 = nb0; cb1 = nb1; ca0 = na0; ca1 = na1; }
  }

  // ---- fused epilogue
  float am0 = 0.f, am1 = 0.f;
  #pragma unroll
  for (int jt = 0; jt < 2; ++jt) {
    #pragma unroll
    for (int q = 0; q < 4; ++q) {
      const int jrow = jt * 16 + lk * 4 + q;
      if (exi && (sexf[jrow] > 0.f)) {
        const float e0 = see[jrow][0], e1 = see[jrow][1];
        const float e2 = see[jrow][2], e3 = see[jrow][3];
        const float pb0 = b10 + a2v0[jt * 4 + q] + acc[jt][0][q];
        const float pb1 = b11 + a2v1[jt * 4 + q] + acc[jt][1][q];
        if (e0 > 0.f) { am0 = fmaxf(am0, fmaxf(fmaf(e0, w40[0], pb0), 0.f));
                        am1 = fmaxf(am1, fmaxf(fmaf(e0, w41[0], pb1), 0.f)); }
        if (e1 > 0.f) { am0 = fmaxf(am0, fmaxf(fmaf(e1, w40[1], pb0), 0.f));
                        am1 = fmaxf(am1, fmaxf(fmaf(e1, w41[1], pb1), 0.f)); }
        if (e2 > 0.f) { am0 = fmaxf(am0, fmaxf(fmaf(e2, w40[2], pb0), 0.f));
                        am1 = fmaxf(am1, fmaxf(fmaf(e2, w41[2], pb1), 0.f)); }
        if (e3 > 0.f) { am0 = fmaxf(am0, fmaxf(fmaf(e3, w40[3], pb0), 0.f));
                        am1 = fmaxf(am1, fmaxf(fmaf(e3, w41[3], pb1), 0.f)); }
      }
    }
  }
  am0 = fmaxf(am0, __shfl_xor(am0, 16));
  am0 = fmaxf(am0, __shfl_xor(am0, 32));
  am1 = fmaxf(am1, __shfl_xor(am1, 16));
  am1 = fmaxf(am1, __shfl_xor(am1, 32));
  if (lk == 0) {  // values >= 0: float bits monotone as uint; max is exact
    atomicMax((unsigned int*)&cf1[i * 256 + c0], __float_as_uint(am0));
    atomicMax((unsigned int*)&cf1[i * 256 + c1], __float_as_uint(am1));
  }
}

// ---------------------------------------------------------------------------
// K4: gemm1 = K=768 MFMA [el_ij | cf1_j | cf1_i] @ [W3_1; W2_1; W1_1] +
// masked relu-max epilogue -> atomicMax into cf2. Pipelined like gemm0.
// grid 512 = (i, jq), 512 thr. LDS 32 x 768 bf16 (48 KB), XOR-swizzled.
// ---------------------------------------------------------------------------
__global__ void __launch_bounds__(512) k_gemm1(
    const float* __restrict__ Arow, const float* __restrict__ Brow,
    const float* __restrict__ bel, const unsigned short* __restrict__ W768F,
    const float* __restrict__ cf1,
    const float* __restrict__ Wop1, const float* __restrict__ bop1,
    const float* __restrict__ exlog, const float* __restrict__ ee_g,
    float* __restrict__ cf2)
{
  const int i  = blockIdx.x >> 2;
  const int jq = blockIdx.x & 3;
  const int t  = threadIdx.x;
  const int w  = t >> 6;
  const int l  = t & 63;
  __shared__ char sEL[32 * 1536];
  __shared__ float see[32][4];
  __shared__ float sexf[32];

  const bool exi = exlog[i] > 0.f;
  const int lr = l & 15, lk = l >> 4;

  // ---- hoisted epilogue operands
  const int c0 = w * 32 + lr, c1 = c0 + 16;
  const float b10 = bop1[c0];
  const float b11 = bop1[c1];
  float w40[4], w41[4];
  #pragma unroll
  for (int tt = 0; tt < 4; ++tt) {
    w40[tt] = Wop1[(768 + tt) * 256 + c0];
    w41[tt] = Wop1[(768 + tt) * 256 + c1];
  }
  if (t < 128)
    see[t >> 2][t & 3] = ee_g[(i * 128 + jq * 32 + (t >> 2)) * 4 + (t & 3)];
  if (t < 32) sexf[t] = exlog[jq * 32 + t];

  // ---- stage [el | cf1_j | cf1_i] tile
  {
    const int row = t >> 4;
    const int sub = t & 15;
    const int kb  = sub * 16;
    const int swz = (row & 7) << 4;
    {
      const float* Ap  = Arow + i * 256 + kb;
      const float* Bp  = Brow + (jq * 32 + row) * 256 + kb;
      const float* blp = bel + kb;
      float e[16];
      #pragma unroll
      for (int q = 0; q < 16; q += 4) {
        float4 av = ld4(Ap + q), bv = ld4(Bp + q), lv = ld4(blp + q);
        e[q+0] = fmaxf(av.x + bv.x + lv.x, 0.f);
        e[q+1] = fmaxf(av.y + bv.y + lv.y, 0.f);
        e[q+2] = fmaxf(av.z + bv.z + lv.z, 0.f);
        e[q+3] = fmaxf(av.w + bv.w + lv.w, 0.f);
      }
      uint4 w0, w1;
      w0.x = pack2(e[0], e[1]);  w0.y = pack2(e[2], e[3]);
      w0.z = pack2(e[4], e[5]);  w0.w = pack2(e[6], e[7]);
      w1.x = pack2(e[8], e[9]);  w1.y = pack2(e[10], e[11]);
      w1.z = pack2(e[12], e[13]); w1.w = pack2(e[14], e[15]);
      *reinterpret_cast<uint4*>(sEL + ((row * 1536 + kb * 2)      ^ swz)) = w0;
      *reinterpret_cast<uint4*>(sEL + ((row * 1536 + kb * 2 + 16) ^ swz)) = w1;
    }
    {
      const float* cj = cf1 + (jq * 32 + row) * 256 + kb;
      float4 v0 = ld4(cj), v1 = ld4(cj + 4), v2 = ld4(cj + 8), v3 = ld4(cj + 12);
      uint4 w0, w1;
      w0.x = pack2(v0.x, v0.y); w0.y = pack2(v0.z, v0.w);
      w0.z = pack2(v1.x, v1.y); w0.w = pack2(v1.z, v1.w);
      w1.x = pack2(v2.x, v2.y); w1.y = pack2(v2.z, v2.w);
      w1.z = pack2(v3.x, v3.y); w1.w = pack2(v3.z, v3.w);
      *reinterpret_cast<uint4*>(sEL + ((row * 1536 + 512 + kb * 2)      ^ swz)) = w0;
      *reinterpret_cast<uint4*>(sEL + ((row * 1536 + 512 + kb * 2 + 16) ^ swz)) = w1;
    }
    {
      const float* ci = cf1 + i * 256 + kb;
      float4 v0 = ld4(ci), v1 = ld4(ci + 4), v2 = ld4(ci + 8), v3 = ld4(ci + 12);
      uint4 w0, w1;
      w0.x = pack2(v0.x, v0.y); w0.y = pack2(v0.z, v0.w);
      w0.z = pack2(v1.x, v1.y); w0.w = pack2(v1.z, v1.w);
      w1.x = pack2(v2.x, v2.y); w1.y = pack2(v2.z, v2.w);
      w1.z = pack2(v3.x, v3.y); w1.w = pack2(v3.z, v3.w);
      *reinterpret_cast<uint4*>(sEL + ((row * 1536 + 1024 + kb * 2)      ^ swz)) = w0;
      *reinterpret_cast<uint4*>(sEL + ((row * 1536 + 1024 + kb * 2 + 16) ^ swz)) = w1;
    }
  }
  __syncthreads();

  // ---- MFMA K=768, depth-1 pipelined
  f32x4 acc[2][2];
  #pragma unroll
  for (int jt = 0; jt < 2; ++jt)
    #pragma unroll
    for (int ct = 0; ct < 2; ++ct)
      acc[jt][ct] = (f32x4){0.f, 0.f, 0.f, 0.f};

  const int swz0 = (lr & 7) << 4;
  bf16x8 cb0 = *reinterpret_cast<const bf16x8*>(W768F + (0 * 16 + w * 2 + 0) * 512 + l * 8);
  bf16x8 cb1 = *reinterpret_cast<const bf16x8*>(W768F + (0 * 16 + w * 2 + 1) * 512 + l * 8);
  bf16x8 ca0 = *reinterpret_cast<const bf16x8*>(sEL + ((lr * 1536 + lk * 16) ^ swz0));
  bf16x8 ca1 = *reinterpret_cast<const bf16x8*>(sEL + (((16 + lr) * 1536 + lk * 16) ^ swz0));
  #pragma unroll
  for (int kc = 0; kc < 24; ++kc) {
    bf16x8 nb0, nb1, na0, na1;
    if (kc < 23) {
      const int kbyte = (kc + 1) * 64 + lk * 16;
      nb0 = *reinterpret_cast<const bf16x8*>(W768F + ((kc + 1) * 16 + w * 2 + 0) * 512 + l * 8);
      nb1 = *reinterpret_cast<const bf16x8*>(W768F + ((kc + 1) * 16 + w * 2 + 1) * 512 + l * 8);
      na0 = *reinterpret_cast<const bf16x8*>(sEL + ((lr * 1536 + kbyte) ^ swz0));
      na1 = *reinterpret_cast<const bf16x8*>(sEL + (((16 + lr) * 1536 + kbyte) ^ swz0));
    }
    acc[0][0] = __builtin_amdgcn_mfma_f32_16x16x32_bf16(ca0, cb0, acc[0][0], 0, 0, 0);
    acc[1][0] = __builtin_amdgcn_mfma_f32_16x16x32_bf16(ca1, cb0, acc[1][0], 0, 0, 0);
    acc[0][1] = __builtin_amdgcn_mfma_f32_16x16x32_bf16(ca0, cb1, acc[0][1], 0, 0, 0);
    acc[1][1] = __builtin_amdgcn_mfma_f32_16x16x32_bf16(ca1, cb1, acc[1][1], 0, 0, 0);
    if (kc < 23) { cb0 = nb0; cb1 = nb1; ca0 = na0; ca1 = na1; }
  }

  // ---- epilogue: acc already holds a1+a2+el@W3
  float am0 = 0.f, am1 = 0.f;
  #pragma unroll
  for (int jt = 0; jt < 2; ++jt) {
    #pragma unroll
    for (int q = 0; q < 4; ++q) {
      const int jrow = jt * 16 + lk * 4 + q;
      if (exi && (sexf[jrow] > 0.f)) {
        const float e0 = see[jrow][0], e1 = see[jrow][1];
        const float e2 = see[jrow][2], e3 = see[jrow][3];
        const float pb0 = b10 + acc[jt][0][q];
        const float pb1 = b11 + acc[jt][1][q];
        if (e0 > 0.f) { am0 = fmaxf(am0, fmaxf(fmaf(e0, w40[0], pb0), 0.f));
                        am1 = fmaxf(am1, fmaxf(fmaf(e0, w41[0], pb1), 0.f)); }
        if (e1 > 0.f) { am0 = fmaxf(am0, fmaxf(fmaf(e1, w40[1], pb0), 0.f));
                        am1 = fmaxf(am1, fmaxf(fmaf(e1, w41[1], pb1), 0.f)); }
        if (e2 > 0.f) { am0 = fmaxf(am0, fmaxf(fmaf(e2, w40[2], pb0), 0.f));
                        am1 = fmaxf(am1, fmaxf(fmaf(e2, w41[2], pb1), 0.f)); }
        if (e3 > 0.f) { am0 = fmaxf(am0, fmaxf(fmaf(e3, w40[3], pb0), 0.f));
                        am1 = fmaxf(am1, fmaxf(fmaf(e3, w41[3], pb1), 0.f)); }
      }
    }
  }
  am0 = fmaxf(am0, __shfl_xor(am0, 16));
  am0 = fmaxf(am0, __shfl_xor(am0, 32));
  am1 = fmaxf(am1, __shfl_xor(am1, 16));
  am1 = fmaxf(am1, __shfl_xor(am1, 32));
  if (lk == 0) {
    atomicMax((unsigned int*)&cf2[i * 256 + c0], __float_as_uint(am0));
    atomicMax((unsigned int*)&cf2[i * 256 + c1], __float_as_uint(am1));
  }
}

// ---------------------------------------------------------------------------
// K5: ch/sem/feats from [cf0|cf1|cf2]. grid 128 (m) x 512 thr (8-way K-split).
// ---------------------------------------------------------------------------
__global__ void __launch_bounds__(512) k_final(
    const float* __restrict__ cf0, const float* __restrict__ cf1,
    const float* __restrict__ cf2,
    const float* __restrict__ Wch, const float* __restrict__ bch,
    const float* __restrict__ Wsem, const float* __restrict__ bsem,
    const float* __restrict__ Wch2, const float* __restrict__ bch2,
    float* __restrict__ out_feats, float* __restrict__ out_sem)
{
  const int m  = blockIdx.x;
  const int t  = threadIdx.x;
  const int hq = (t & 63) << 2;
  const int kg = t >> 6;            // 0..7
  __shared__ float sall[768];
  __shared__ float sch[256];
  __shared__ float red[8][256];
  __shared__ float redS[8][64];

  if (t < 256) {
    sall[t]       = cf0[m * 256 + t];
    sall[256 + t] = cf1[m * 256 + t];
    sall[512 + t] = cf2[m * 256 + t];
  }
  __syncthreads();

  {
    float4 acc = make_float4(0.f, 0.f, 0.f, 0.f);
    const int k0 = kg * 96;
    #pragma unroll 8
    for (int k = k0; k < k0 + 96; ++k)
      acc = fma4(sall[k], ld4(Wch + k * 256 + hq), acc);
    st4(&red[kg][hq], acc);
  }
  __syncthreads();
  if (kg == 0) {
    float4 r = ld4(&red[0][hq]);
    #pragma unroll
    for (int g2 = 1; g2 < 8; ++g2) r = add4(r, ld4(&red[g2][hq]));
    r = relu4(add4(r, ld4(bch + hq)));
    st4(&sch[hq], r);
  }
  __syncthreads();

  {
    float4 f = make_float4(0.f, 0.f, 0.f, 0.f);
    const int k0 = kg * 32;
    #pragma unroll 8
    for (int k = k0; k < k0 + 32; ++k)
      f = fma4(sch[k], ld4(Wch2 + k * 256 + hq), f);
    const int s = t & 63;
    float sv = 0.f;
    if (s < 57) {
      #pragma unroll 8
      for (int k = k0; k < k0 + 32; ++k)
        sv = fmaf(sch[k], Wsem[k * 57 + s], sv);
    }
    redS[kg][s] = sv;
    st4(&red[kg][hq], f);
  }
  __syncthreads();
  if (kg == 0) {
    float4 r = ld4(&red[0][hq]);
    #pragma unroll
    for (int g2 = 1; g2 < 8; ++g2) r = add4(r, ld4(&red[g2][hq]));
    r = relu4(add4(r, ld4(bch2 + hq)));
    st4(&out_feats[m * 256 + hq], r);
  }
  if (t < 57) {
    float s2 = bsem[t];
    #pragma unroll
    for (int g2 = 0; g2 < 8; ++g2) s2 += redS[g2][t];
    out_sem[m * 57 + t] = s2;
  }
}

// ---------------------------------------------------------------------------
extern "C" void kernel_launch(void* const* d_in, const int* in_sizes, int n_in,
                              void* d_out, int out_size, void* d_ws, size_t ws_size,
                              hipStream_t stream)
{
  const float* pf   = (const float*)d_in[0];
  const float* Wp   = (const float*)d_in[1];
  const float* bp   = (const float*)d_in[2];
  const float* Wex  = (const float*)d_in[3];
  const float* bex  = (const float*)d_in[4];
  const float* Wel  = (const float*)d_in[5];
  const float* bel  = (const float*)d_in[6];
  const float* Wee  = (const float*)d_in[7];
  const float* bee  = (const float*)d_in[8];
  const float* Wop  = (const float*)d_in[9];
  const float* bop  = (const float*)d_in[10];
  const float* Wch  = (const float*)d_in[11];
  const float* bch  = (const float*)d_in[12];
  const float* Wsem = (const float*)d_in[13];
  const float* bsem = (const float*)d_in[14];
  const float* Wch2 = (const float*)d_in[15];
  const float* bch2 = (const float*)d_in[16];

  // Output layout (fp32): feats | sem | exists | ee
  float* out_feats = (float*)d_out;
  float* out_sem   = out_feats + M_ * F_;
  float* out_ex    = out_sem + M_ * NSEM_;
  float* out_ee    = out_ex + M_;

  // Workspace (floats)
  float* ws = (float*)d_ws;
  float* cf0 = ws;                     // 32768
  float* cf1 = ws + 32768;             // 32768 (atomicMax target, zeroed in stage1)
  float* cf2 = ws + 65536;             // 32768 (atomicMax target, zeroed in stage1)
  float* Ab  = ws + 98304;             // 32768
  float* Bb  = ws + 131072;            // 32768
  float* a1  = ws + 163840;            // 32768
  float* a2  = ws + 196608;            // 32768
  float* part = ws + 229376;           // 32*32768 = 1048576 floats (4 MB)
  unsigned short* W36F  = (unsigned short*)(ws + 1277952);  // 65536 bf16
  unsigned short* W768F = (unsigned short*)(ws + 1310720);  // 196608 bf16

  const float* Wop0 = Wop;               // iteration 0 block (772*256 floats)
  const float* Wop1 = Wop + 197632;      // iteration 1 block

  k_parent<<<1024, 256, 0, stream>>>(pf, Wp, Wop, part, W36F, W768F);
  k_stage1<<<256, 256, 0, stream>>>(part, bp, Wel, Wop0, Wex, bex,
                                    cf0, Ab, Bb, a1, a2, cf1, cf2, out_ex);
  k_gemm0<<<512, 512, 0, stream>>>(Ab, Bb, bel, W36F, Wee, bee,
                                   a1, a2, Wop0, bop, out_ex, out_ee, cf1);
  k_gemm1<<<512, 512, 0, stream>>>(Ab, Bb, bel, W768F, cf1,
                                   Wop1, bop + 256, out_ex, out_ee, cf2);
  k_final<<<128, 512, 0, stream>>>(cf0, cf1, cf2, Wch, bch, Wsem, bsem,
                                   Wch2, bch2, out_feats, out_sem);
}